// Round 8
// baseline (8090.646 us; speedup 1.0000x reference)
//
#include <hip/hip_runtime.h>
#include <hip/hip_bf16.h>
#include <stdint.h>

#define N_NODES 100000
#define N_REL   16
#define N_EDGE  50000
#define DIM     500
#define TOT_E   (N_REL * N_EDGE)      // 800,000
#define CNT_N   (N_REL * N_NODES)     // 1,600,000

// ws layout: inv f32 [0, 6.4MB), h1 bf16 [6.4MB, 106.4MB)
#define INV_OFF 0ull
#define H1_OFF  6400000ull

// ---------------- threefry2x32 (core verified vs Random123 KAT) ----------------
__device__ __forceinline__ uint32_t rotl32(uint32_t x, int d) {
    return (x << d) | (x >> (32 - d));
}

// full threefry2x32 with key (0,42); returns BOTH output lanes
__device__ __forceinline__ void tf2x32(uint32_t x0, uint32_t x1,
                                       uint32_t& o0, uint32_t& o1) {
    const uint32_t ks0 = 0u, ks1 = 42u, ks2 = 0u ^ 42u ^ 0x1BD11BDAu;
    const int RA[4] = {13, 15, 26, 6};
    const int RB[4] = {17, 29, 16, 24};
    x0 += ks0; x1 += ks1;
#pragma unroll
    for (int i = 0; i < 4; i++) { x0 += x1; x1 = rotl32(x1, RA[i]); x1 ^= x0; }
    x0 += ks1; x1 += ks2 + 1u;
#pragma unroll
    for (int i = 0; i < 4; i++) { x0 += x1; x1 = rotl32(x1, RB[i]); x1 ^= x0; }
    x0 += ks2; x1 += ks0 + 2u;
#pragma unroll
    for (int i = 0; i < 4; i++) { x0 += x1; x1 = rotl32(x1, RA[i]); x1 ^= x0; }
    x0 += ks0; x1 += ks1 + 3u;
#pragma unroll
    for (int i = 0; i < 4; i++) { x0 += x1; x1 = rotl32(x1, RB[i]); x1 ^= x0; }
    x0 += ks1; x1 += ks2 + 4u;
#pragma unroll
    for (int i = 0; i < 4; i++) { x0 += x1; x1 = rotl32(x1, RA[i]); x1 ^= x0; }
    x0 += ks2; x1 += ks0 + 5u;
    o0 = x0; o1 = x1;
}

// ROUND-8 CHANGE (only variable): partitionable-mode 32-bit draw is the
// XOR FOLD of the two cipher output lanes (jax/_src/prng.py,
// _threefry_random_bits_partitionable: bit_width<64 -> bits1 ^ bits2).
// Counter for flat index j is 64-bit iota -> (hi,lo)=(0,j).
// keep <=> uniform<0.5 <=> MSB(bits1^bits2)==0.
__device__ __forceinline__ bool edge_keep(uint32_t j) {
    uint32_t b0, b1;
    tf2x32(0u, j, b0, b1);
    return ((b0 ^ b1) >> 31) == 0u;
}

// ---------------- zero the cnt scratch (head of d_out) ----------------
__global__ __launch_bounds__(256) void zero_kernel(float* __restrict__ p, int n) {
    int t = blockIdx.x * blockDim.x + threadIdx.x;
    if (t < n) p[t] = 0.f;
}

// ---------------- count kept edges per (relation,dst) into d_out head ----------------
__global__ __launch_bounds__(256) void count_kernel(
        const int* __restrict__ eidx, float* __restrict__ cnt_out) {
    int tid = blockIdx.x * blockDim.x + threadIdx.x;
    if (tid >= TOT_E) return;
    if (edge_keep((uint32_t)tid)) {
        int r = tid / N_EDGE;
        int e = tid - r * N_EDGE;
        int dst = eidx[(r * 2 + 1) * N_EDGE + e];
        atomicAdd(&cnt_out[r * N_NODES + dst], 1.0f);
    }
}

// ---------------- inv = 1/max(cnt,1), plain-stored into ws ----------------
__global__ __launch_bounds__(256) void inv_kernel(const float* __restrict__ cnt_out,
                                                  float* __restrict__ inv_ws) {
    int t = blockIdx.x * blockDim.x + threadIdx.x;
    if (t < CNT_N) inv_ws[t] = 1.0f / fmaxf(cnt_out[t], 1.0f);
}

// ---------------- tiled GEMM: C[M,500] = A[M,500] @ W[500,500] ----------------
template <bool BF16A>
__device__ __forceinline__ float loadA(const void* __restrict__ A, long idx) {
    if constexpr (BF16A) {
        uint32_t u = ((const uint16_t*)A)[idx];
        return __uint_as_float(u << 16);
    } else {
        return ((const float*)A)[idx];
    }
}

template <bool BF16A>
__global__ __launch_bounds__(256) void gemm_kernel(
        const void* __restrict__ A, const float* __restrict__ W,
        float* __restrict__ C, int M) {
    const int BM = 64, BN = 64, BK = 16;
    __shared__ float As[BK][BM + 4];
    __shared__ float Bs[BK][BN + 4];
    int m0 = blockIdx.x * BM;
    int n0 = blockIdx.y * BN;
    int tid = threadIdx.x;
    int tx = tid & 15, ty = tid >> 4;
    float acc[4][4] = {};
    for (int k0 = 0; k0 < DIM; k0 += BK) {
#pragma unroll
        for (int i = 0; i < 4; i++) {
            int idx = tid + i * 256;
            int m = idx >> 4, k = idx & 15;
            int gm = m0 + m, gk = k0 + k;
            float v = 0.f;
            if (gm < M && gk < DIM) v = loadA<BF16A>(A, (long)gm * DIM + gk);
            As[k][m] = v;
        }
#pragma unroll
        for (int i = 0; i < 4; i++) {
            int idx = tid + i * 256;
            int k = idx >> 6, n = idx & 63;
            int gk = k0 + k, gn = n0 + n;
            float v = 0.f;
            if (gk < DIM && gn < DIM) v = W[gk * DIM + gn];
            Bs[k][n] = v;
        }
        __syncthreads();
#pragma unroll
        for (int kk = 0; kk < BK; kk++) {
            float a[4], b[4];
#pragma unroll
            for (int i = 0; i < 4; i++) a[i] = As[kk][ty * 4 + i];
#pragma unroll
            for (int j = 0; j < 4; j++) b[j] = Bs[kk][tx * 4 + j];
#pragma unroll
            for (int i = 0; i < 4; i++)
#pragma unroll
                for (int j = 0; j < 4; j++)
                    acc[i][j] = fmaf(a[i], b[j], acc[i][j]);
        }
        __syncthreads();
    }
#pragma unroll
    for (int i = 0; i < 4; i++) {
        int gm = m0 + ty * 4 + i;
        if (gm >= M) continue;
#pragma unroll
        for (int j = 0; j < 4; j++) {
            int gn = n0 + tx * 4 + j;
            if (gn < DIM) C[(long)gm * DIM + gn] = acc[i][j];
        }
    }
}

// ---------------- message + normalized scatter-add, grid-stride over edges ----------------
template <bool BF16H>
__global__ __launch_bounds__(128) void msg_scatter_kernel(
        const void* __restrict__ h, const float* __restrict__ w_rel,
        const int* __restrict__ eidx, const float* __restrict__ inv_ws,
        float* __restrict__ out) {
    __shared__ float hs[DIM];
    int tid = threadIdx.x;
    for (int b = blockIdx.x; b < TOT_E; b += gridDim.x) {
        if (!edge_keep((uint32_t)b)) continue;     // uniform across block
        int r = b / N_EDGE;
        int e = b - r * N_EDGE;
        int src = eidx[(r * 2 + 0) * N_EDGE + e];
        int dst = eidx[(r * 2 + 1) * N_EDGE + e];
        for (int j = tid; j < DIM; j += 128)
            hs[j] = loadA<BF16H>(h, (long)src * DIM + j);
        __syncthreads();
        float inv = inv_ws[r * N_NODES + dst];
        const float* w = w_rel + (size_t)r * 2500;  // (100 blocks) x (5 in x 5 out)
        if (tid < 125) {
#pragma unroll
            for (int q = 0; q < 4; q++) {
                int j = tid * 4 + q;                // output dim 0..499
                int blk = j / 5, c = j - blk * 5;
                float s = 0.f;
#pragma unroll
                for (int i = 0; i < 5; i++)
                    s = fmaf(hs[blk * 5 + i], w[blk * 25 + i * 5 + c], s);
                atomicAdd(&out[(size_t)dst * DIM + j], s * inv);
            }
        }
        __syncthreads();   // protect hs before next iteration
    }
}

// ---------------- relu(f32) -> bf16 (RNE) into ws ----------------
__global__ __launch_bounds__(256) void relu_conv_kernel(
        const float4* __restrict__ in, ushort4* __restrict__ out, int n4) {
    int t = blockIdx.x * blockDim.x + threadIdx.x;
    if (t >= n4) return;
    float4 v = in[t];
    float f[4] = {fmaxf(v.x, 0.f), fmaxf(v.y, 0.f), fmaxf(v.z, 0.f), fmaxf(v.w, 0.f)};
    ushort4 o;
    uint16_t* op = (uint16_t*)&o;
#pragma unroll
    for (int i = 0; i < 4; i++) {
        uint32_t u = __float_as_uint(f[i]);
        u += 0x7FFFu + ((u >> 16) & 1u);
        op[i] = (uint16_t)(u >> 16);
    }
    out[t] = o;
}

__global__ __launch_bounds__(256) void relu_kernel(float4* __restrict__ x, int n4) {
    int t = blockIdx.x * blockDim.x + threadIdx.x;
    if (t < n4) {
        float4 v = x[t];
        v.x = fmaxf(v.x, 0.f); v.y = fmaxf(v.y, 0.f);
        v.z = fmaxf(v.z, 0.f); v.w = fmaxf(v.w, 0.f);
        x[t] = v;
    }
}

extern "C" void kernel_launch(void* const* d_in, const int* in_sizes, int n_in,
                              void* d_out, int out_size, void* d_ws, size_t ws_size,
                              hipStream_t stream) {
    // Resolve inputs by element count (robust to order; 1-before-2 for duplicates).
    const float* x       = nullptr;
    const float* w_rel1  = nullptr;
    const float* w_rel2  = nullptr;
    const float* w_self1 = nullptr;
    const float* w_self2 = nullptr;
    const int*   eidx    = nullptr;
    for (int i = 0; i < n_in; i++) {
        int s = in_sizes[i];
        if (s == N_NODES * DIM) {
            x = (const float*)d_in[i];
        } else if (s == N_REL * 100 * 25) {
            if (!w_rel1) w_rel1 = (const float*)d_in[i];
            else         w_rel2 = (const float*)d_in[i];
        } else if (s == DIM * DIM) {
            if (!w_self1) w_self1 = (const float*)d_in[i];
            else          w_self2 = (const float*)d_in[i];
        } else if (s == N_REL * 2 * N_EDGE) {
            eidx = (const int*)d_in[i];
        }
    }
    float* out = (float*)d_out;

    char* ws = (char*)d_ws;
    float*    inv = (float*)(ws + INV_OFF);     // 1.6M f32 (plain stores only)
    uint16_t* h1  = (uint16_t*)(ws + H1_OFF);   // 50M bf16 (plain stores only)

    // cnt in the head of d_out (HW f32 atomics); L1 GEMM overwrites d_out after.
    zero_kernel<<<(CNT_N + 255) / 256, 256, 0, stream>>>(out, CNT_N);
    count_kernel<<<(TOT_E + 255) / 256, 256, 0, stream>>>(eidx, out);
    inv_kernel<<<(CNT_N + 255) / 256, 256, 0, stream>>>(out, inv);

    dim3 ggrid((N_NODES + 63) / 64, (DIM + 63) / 64);
    int n4 = N_NODES * DIM / 4;

    // layer 1: d_out(f32) = x @ w_self1 + messages(x); h1(bf16) = relu(d_out)
    gemm_kernel<false><<<ggrid, 256, 0, stream>>>(x, w_self1, out, N_NODES);
    msg_scatter_kernel<false><<<2048, 128, 0, stream>>>(x, w_rel1, eidx, inv, out);
    relu_conv_kernel<<<(n4 + 255) / 256, 256, 0, stream>>>((const float4*)out, (ushort4*)h1, n4);

    // layer 2: d_out = relu(h1 @ w_self2 + messages(h1))
    gemm_kernel<true><<<ggrid, 256, 0, stream>>>(h1, w_self2, out, N_NODES);
    msg_scatter_kernel<true><<<2048, 128, 0, stream>>>(h1, w_rel2, eidx, inv, out);
    relu_kernel<<<(n4 + 255) / 256, 256, 0, stream>>>((float4*)out, n4);
}

// Round 9
// 1888.235 us; speedup vs baseline: 4.2848x; 4.2848x over previous
//
#include <hip/hip_runtime.h>
#include <hip/hip_bf16.h>
#include <stdint.h>

#define N_NODES 100000
#define N_REL   16
#define N_EDGE  50000
#define DIM     500
#define TOT_E   (N_REL * N_EDGE)      // 800,000
#define CNT_N   (N_REL * N_NODES)     // 1,600,000

// ws layout (all 16B-aligned):
#define INV_OFF   0ull            // 1.6M u32 cnt -> f32 inv (6,400,000 B)
#define DEG_OFF   6400000ull      // 100k u32
#define ROW_OFF   6800000ull      // 100001 u32
#define SCANP_OFF 7201000ull      // 128 u32
#define CURS_OFF  7210000ull      // 100k u32
#define ELIST_OFF 7610000ull      // 800k u32
#define WB1_OFF   10810000ull     // 512*512 bf16 (524,288 B)
#define WB2_OFF   11340000ull     // 512*512 bf16
#define H1_OFF    11870000ull     // 50M bf16 (x_bf16 then h1; sequential reuse)
                                  // end: 111,870,000 B

typedef __attribute__((ext_vector_type(8))) short bf16x8;
typedef __attribute__((ext_vector_type(4))) float f32x4;

// ---------------- threefry2x32, partitionable-mode mask (R8-verified) ----------------
__device__ __forceinline__ uint32_t rotl32(uint32_t x, int d) {
    return (x << d) | (x >> (32 - d));
}
__device__ __forceinline__ bool edge_keep(uint32_t j) {
    uint32_t x0 = 0u, x1 = j;
    const uint32_t ks0 = 0u, ks1 = 42u, ks2 = 0u ^ 42u ^ 0x1BD11BDAu;
    const int RA[4] = {13, 15, 26, 6};
    const int RB[4] = {17, 29, 16, 24};
    x0 += ks0; x1 += ks1;
#pragma unroll
    for (int i = 0; i < 4; i++) { x0 += x1; x1 = rotl32(x1, RA[i]); x1 ^= x0; }
    x0 += ks1; x1 += ks2 + 1u;
#pragma unroll
    for (int i = 0; i < 4; i++) { x0 += x1; x1 = rotl32(x1, RB[i]); x1 ^= x0; }
    x0 += ks2; x1 += ks0 + 2u;
#pragma unroll
    for (int i = 0; i < 4; i++) { x0 += x1; x1 = rotl32(x1, RA[i]); x1 ^= x0; }
    x0 += ks0; x1 += ks1 + 3u;
#pragma unroll
    for (int i = 0; i < 4; i++) { x0 += x1; x1 = rotl32(x1, RB[i]); x1 ^= x0; }
    x0 += ks1; x1 += ks2 + 4u;
#pragma unroll
    for (int i = 0; i < 4; i++) { x0 += x1; x1 = rotl32(x1, RA[i]); x1 ^= x0; }
    x0 += ks2; x1 += ks0 + 5u;
    return ((x0 ^ x1) >> 31) == 0u;    // XOR fold, MSB==0 <=> keep
}

__device__ __forceinline__ uint16_t f2bf(float f) {
    uint32_t u = __float_as_uint(f);
    u += 0x7FFFu + ((u >> 16) & 1u);
    return (uint16_t)(u >> 16);
}

template <bool BF16A>
__device__ __forceinline__ float loadA(const void* __restrict__ A, long idx) {
    if constexpr (BF16A) {
        uint32_t u = ((const uint16_t*)A)[idx];
        return __uint_as_float(u << 16);
    } else {
        return ((const float*)A)[idx];
    }
}

// ---------------- CSR build ----------------
__global__ __launch_bounds__(256) void zero_kernel(uint32_t* __restrict__ p, int n) {
    int t = blockIdx.x * blockDim.x + threadIdx.x;
    if (t < n) p[t] = 0u;
}

__global__ __launch_bounds__(256) void count_kernel(
        const int* __restrict__ eidx, uint32_t* __restrict__ cnt,
        uint32_t* __restrict__ deg) {
    int tid = blockIdx.x * blockDim.x + threadIdx.x;
    if (tid >= TOT_E) return;
    if (edge_keep((uint32_t)tid)) {
        int r = tid / N_EDGE;
        int e = tid - r * N_EDGE;
        int dst = eidx[(r * 2 + 1) * N_EDGE + e];
        atomicAdd(&cnt[r * N_NODES + dst], 1u);
        atomicAdd(&deg[dst], 1u);
    }
}

__global__ __launch_bounds__(256) void inv_kernel(uint32_t* __restrict__ cnt_u,
                                                  float* __restrict__ inv) {
    int t = blockIdx.x * blockDim.x + threadIdx.x;
    if (t < CNT_N) {
        float c = (float)cnt_u[t];
        inv[t] = 1.0f / fmaxf(c, 1.0f);
    }
}

__global__ __launch_bounds__(256) void scan1_kernel(
        const uint32_t* __restrict__ deg, uint32_t* __restrict__ rowptr,
        uint32_t* __restrict__ scanp) {
    __shared__ uint32_t sh[256];
    int b = blockIdx.x, t = threadIdx.x;
    int base = b * 1024 + t * 4;
    uint32_t x[4];
#pragma unroll
    for (int i = 0; i < 4; i++) x[i] = (base + i < N_NODES) ? deg[base + i] : 0u;
    uint32_t s = x[0] + x[1] + x[2] + x[3];
    sh[t] = s; __syncthreads();
    for (int off = 1; off < 256; off <<= 1) {
        uint32_t v = (t >= off) ? sh[t - off] : 0u;
        __syncthreads();
        sh[t] += v;
        __syncthreads();
    }
    uint32_t run = sh[t] - s;   // exclusive prefix
    if (t == 255) scanp[b] = sh[255];
#pragma unroll
    for (int i = 0; i < 4; i++) {
        if (base + i < N_NODES) rowptr[base + i] = run;
        run += x[i];
    }
}

__global__ __launch_bounds__(128) void scan2_kernel(
        uint32_t* __restrict__ scanp, uint32_t* __restrict__ rowptr, int nb) {
    __shared__ uint32_t sh[128];
    int t = threadIdx.x;
    uint32_t v = (t < nb) ? scanp[t] : 0u;
    sh[t] = v; __syncthreads();
    for (int off = 1; off < 128; off <<= 1) {
        uint32_t u = (t >= off) ? sh[t - off] : 0u;
        __syncthreads();
        sh[t] += u;
        __syncthreads();
    }
    if (t < nb) scanp[t] = sh[t] - v;        // exclusive block offsets
    if (t == 127) rowptr[N_NODES] = sh[127]; // grand total
}

__global__ __launch_bounds__(256) void scan3_kernel(
        uint32_t* __restrict__ rowptr, const uint32_t* __restrict__ scanp,
        uint32_t* __restrict__ curs) {
    int b = blockIdx.x, t = threadIdx.x;
    int base = b * 1024 + t * 4;
    uint32_t off = scanp[b];
#pragma unroll
    for (int i = 0; i < 4; i++) {
        int idx = base + i;
        if (idx < N_NODES) {
            uint32_t v = rowptr[idx] + off;
            rowptr[idx] = v;
            curs[idx] = v;
        }
    }
}

__global__ __launch_bounds__(256) void scatter_kernel(
        const int* __restrict__ eidx, uint32_t* __restrict__ curs,
        uint32_t* __restrict__ elist) {
    int tid = blockIdx.x * blockDim.x + threadIdx.x;
    if (tid >= TOT_E) return;
    if (edge_keep((uint32_t)tid)) {
        int r = tid / N_EDGE;
        int e = tid - r * N_EDGE;
        int dst = eidx[(r * 2 + 1) * N_EDGE + e];
        uint32_t pos = atomicAdd(&curs[dst], 1u);
        elist[pos] = (uint32_t)tid;
    }
}

// ---------------- dtype conversion ----------------
__global__ __launch_bounds__(256) void conv_x_kernel(
        const float4* __restrict__ in, ushort4* __restrict__ outp, int n4) {
    int t = blockIdx.x * blockDim.x + threadIdx.x;
    if (t >= n4) return;
    float4 v = in[t];
    ushort4 o;
    o.x = f2bf(v.x); o.y = f2bf(v.y); o.z = f2bf(v.z); o.w = f2bf(v.w);
    outp[t] = o;
}

// Bt[n][k] = W[k][n], padded to 512x512 with zeros
__global__ __launch_bounds__(256) void conv_w_kernel(
        const float* __restrict__ W, uint16_t* __restrict__ Bt) {
    int idx = blockIdx.x * 256 + threadIdx.x;   // 512*512
    int n = idx >> 9, k = idx & 511;
    float v = (n < DIM && k < DIM) ? W[k * DIM + n] : 0.f;
    Bt[idx] = f2bf(v);
}

// ---------------- MFMA bf16 GEMM: C[M,500] = A[M,500] @ W[500,500] ----------------
// A bf16 [M][500]; Bt bf16 [512][512] (Bt[n][k]=W[k][n]); C f32.
// BM=64, BN=64, BK=64; 4 waves, wave w handles rows 16w..16w+15 x all 64 cols.
__global__ __launch_bounds__(256) void gemm_mfma_kernel(
        const uint16_t* __restrict__ A, const uint16_t* __restrict__ Bt,
        float* __restrict__ C, int M) {
    __shared__ uint16_t As[64][72];   // +8 pad: row stride 144B breaks bank conflicts
    __shared__ uint16_t Bs[64][72];
    int m0 = blockIdx.x * 64;
    int n0 = blockIdx.y * 64;
    int t = threadIdx.x;
    int wave = t >> 6, lane = t & 63;
    int row_s = t >> 2;              // staging row 0..63
    int k4 = (t & 3) * 16;           // staging k offset {0,16,32,48}
    f32x4 acc[4] = {};

    for (int k0 = 0; k0 < 512; k0 += 64) {
        // stage A tile (64 rows x 64 k)
        {
            int gm = m0 + row_s;
            int gk = k0 + k4;
            uint16_t* dst = &As[row_s][k4];
            if (gm < M && gk + 15 < DIM) {
                *(bf16x8*)dst       = *(const bf16x8*)&A[(long)gm * DIM + gk];
                *(bf16x8*)(dst + 8) = *(const bf16x8*)&A[(long)gm * DIM + gk + 8];
            } else {
#pragma unroll
                for (int i = 0; i < 16; i++)
                    dst[i] = (gm < M && gk + i < DIM) ? A[(long)gm * DIM + gk + i] : (uint16_t)0;
            }
        }
        // stage B tile: Bs[n][k] from padded Bt (always in-bounds)
        {
            uint16_t* dst = &Bs[row_s][k4];
            const uint16_t* srcp = &Bt[(n0 + row_s) * 512 + k0 + k4];
            *(bf16x8*)dst       = *(const bf16x8*)srcp;
            *(bf16x8*)(dst + 8) = *(const bf16x8*)(srcp + 8);
        }
        __syncthreads();

        int rA = (wave << 4) + (lane & 15);
        int ks = (lane >> 4) * 8;
        bf16x8 a0 = *(const bf16x8*)&As[rA][ks];
        bf16x8 a1 = *(const bf16x8*)&As[rA][32 + ks];
#pragma unroll
        for (int nt = 0; nt < 4; nt++) {
            int cB = (nt << 4) + (lane & 15);
            bf16x8 b0 = *(const bf16x8*)&Bs[cB][ks];
            bf16x8 b1 = *(const bf16x8*)&Bs[cB][32 + ks];
            acc[nt] = __builtin_amdgcn_mfma_f32_16x16x32_bf16(a0, b0, acc[nt], 0, 0, 0);
            acc[nt] = __builtin_amdgcn_mfma_f32_16x16x32_bf16(a1, b1, acc[nt], 0, 0, 0);
        }
        __syncthreads();
    }

    // C/D layout (m89-verified): col = lane&15, row = (lane>>4)*4 + reg
    int rbase = m0 + (wave << 4) + ((lane >> 4) << 2);
    int cl = lane & 15;
#pragma unroll
    for (int nt = 0; nt < 4; nt++) {
        int col = n0 + (nt << 4) + cl;
        if (col < DIM) {
#pragma unroll
            for (int q = 0; q < 4; q++) {
                int rr = rbase + q;
                if (rr < M) C[(long)rr * DIM + col] = acc[nt][q];
            }
        }
    }
}

// ---------------- per-dst gather of messages + fused add/relu epilogue ----------------
template <bool BF16H, bool OUT_BF16>
__global__ __launch_bounds__(256) void gather_kernel(
        const void* __restrict__ h, const float* __restrict__ w_rel,
        const int* __restrict__ eidx, const float* __restrict__ inv_ws,
        const uint32_t* __restrict__ rowptr, const uint32_t* __restrict__ elist,
        const float* __restrict__ self_in, float* __restrict__ out_f32,
        uint16_t* __restrict__ out_bf16) {
    int n = blockIdx.x;
    int t = threadIdx.x;
    __shared__ float hs[DIM];
    __shared__ float acc[DIM];
    for (int j = t; j < DIM; j += 256) acc[j] = 0.f;
    uint32_t s = rowptr[n], e = rowptr[n + 1];
    for (uint32_t p = s; p < e; p++) {
        uint32_t jid = elist[p];
        int r = jid / N_EDGE;
        int ee = jid - r * N_EDGE;
        int src = eidx[(r * 2 + 0) * N_EDGE + ee];
        float inv = inv_ws[r * N_NODES + n];
        for (int j = t; j < DIM; j += 256)
            hs[j] = loadA<BF16H>(h, (long)src * DIM + j);
        __syncthreads();
        const float* w = w_rel + (size_t)r * 2500;
        for (int j = t; j < DIM; j += 256) {
            int blk = j / 5, c = j - blk * 5;
            float sm = 0.f;
#pragma unroll
            for (int i = 0; i < 5; i++)
                sm = fmaf(hs[blk * 5 + i], w[blk * 25 + i * 5 + c], sm);
            acc[j] += inv * sm;
        }
        __syncthreads();   // hs reused next edge
    }
    for (int j = t; j < DIM; j += 256) {
        float v = self_in[(long)n * DIM + j] + acc[j];
        v = fmaxf(v, 0.f);
        if (OUT_BF16) out_bf16[(long)n * DIM + j] = f2bf(v);
        else          out_f32[(long)n * DIM + j] = v;
    }
}

extern "C" void kernel_launch(void* const* d_in, const int* in_sizes, int n_in,
                              void* d_out, int out_size, void* d_ws, size_t ws_size,
                              hipStream_t stream) {
    const float* x       = nullptr;
    const float* w_rel1  = nullptr;
    const float* w_rel2  = nullptr;
    const float* w_self1 = nullptr;
    const float* w_self2 = nullptr;
    const int*   eidx    = nullptr;
    for (int i = 0; i < n_in; i++) {
        int s = in_sizes[i];
        if (s == N_NODES * DIM) {
            x = (const float*)d_in[i];
        } else if (s == N_REL * 100 * 25) {
            if (!w_rel1) w_rel1 = (const float*)d_in[i];
            else         w_rel2 = (const float*)d_in[i];
        } else if (s == DIM * DIM) {
            if (!w_self1) w_self1 = (const float*)d_in[i];
            else          w_self2 = (const float*)d_in[i];
        } else if (s == N_REL * 2 * N_EDGE) {
            eidx = (const int*)d_in[i];
        }
    }
    float* out = (float*)d_out;

    char* ws = (char*)d_ws;
    uint32_t* cnt_u  = (uint32_t*)(ws + INV_OFF);
    float*    inv    = (float*)(ws + INV_OFF);
    uint32_t* deg    = (uint32_t*)(ws + DEG_OFF);
    uint32_t* rowptr = (uint32_t*)(ws + ROW_OFF);
    uint32_t* scanp  = (uint32_t*)(ws + SCANP_OFF);
    uint32_t* curs   = (uint32_t*)(ws + CURS_OFF);
    uint32_t* elist  = (uint32_t*)(ws + ELIST_OFF);
    uint16_t* wb1    = (uint16_t*)(ws + WB1_OFF);
    uint16_t* wb2    = (uint16_t*)(ws + WB2_OFF);
    uint16_t* h1     = (uint16_t*)(ws + H1_OFF);   // x_bf16 during L1 GEMM, then h1

    const int NB = (N_NODES + 1023) / 1024;        // 98 scan blocks

    // CSR build
    zero_kernel<<<(CNT_N + N_NODES + 255) / 256, 256, 0, stream>>>(cnt_u, CNT_N + N_NODES);
    count_kernel<<<(TOT_E + 255) / 256, 256, 0, stream>>>(eidx, cnt_u, deg);
    inv_kernel<<<(CNT_N + 255) / 256, 256, 0, stream>>>(cnt_u, inv);
    scan1_kernel<<<NB, 256, 0, stream>>>(deg, rowptr, scanp);
    scan2_kernel<<<1, 128, 0, stream>>>(scanp, rowptr, NB);
    scan3_kernel<<<NB, 256, 0, stream>>>(rowptr, scanp, curs);
    scatter_kernel<<<(TOT_E + 255) / 256, 256, 0, stream>>>(eidx, curs, elist);

    // bf16 conversions
    conv_x_kernel<<<(N_NODES * DIM / 4 + 255) / 256, 256, 0, stream>>>(
        (const float4*)x, (ushort4*)h1, N_NODES * DIM / 4);
    conv_w_kernel<<<512 * 512 / 256, 256, 0, stream>>>(w_self1, wb1);
    conv_w_kernel<<<512 * 512 / 256, 256, 0, stream>>>(w_self2, wb2);

    dim3 ggrid((N_NODES + 63) / 64, 8);

    // layer 1: out(f32) = x_bf16 @ w_self1 (MFMA); h1 = relu(out + msgs(x_f32)) [bf16]
    gemm_mfma_kernel<<<ggrid, 256, 0, stream>>>(h1, wb1, out, N_NODES);
    gather_kernel<false, true><<<N_NODES, 256, 0, stream>>>(
        x, w_rel1, eidx, inv, rowptr, elist, out, nullptr, h1);

    // layer 2: out(f32) = h1 @ w_self2 (MFMA); out = relu(out + msgs(h1))
    gemm_mfma_kernel<<<ggrid, 256, 0, stream>>>(h1, wb2, out, N_NODES);
    gather_kernel<true, false><<<N_NODES, 256, 0, stream>>>(
        h1, w_rel2, eidx, inv, rowptr, elist, out, out, nullptr);
}